// Round 1
// baseline (1430.590 us; speedup 1.0000x reference)
//
#include <hip/hip_runtime.h>
#include <hip/hip_bf16.h>

#define K_PTS 128
#define DIM   512
#define BK    32
#define XS_STRIDE 132   // padded leading dim for transposed staging (bank-conflict mitigation, 16B-aligned)

__device__ __forceinline__ int rdlane_i(int v, int lane) {
    return __builtin_amdgcn_readlane(v, lane);
}
__device__ __forceinline__ float rdlane_f(float v, int lane) {
    return __int_as_float(__builtin_amdgcn_readlane(__float_as_int(v), lane));
}

// One block per batch: compute 128x128 squared-distance cost matrix into LDS,
// then solve the LAP (Jonker-Volgenant shortest augmenting path) with wave 0,
// and atomically accumulate the optimal assignment cost into *out.
__global__ __launch_bounds__(256, 2)
void hungarian_mse_kernel(const float* __restrict__ X, const float* __restrict__ Y,
                          float* __restrict__ out, float inv_total) {
    const int b = blockIdx.x;
    const int t = threadIdx.x;

    __shared__ float A[K_PTS * K_PTS];      // cost matrix; doubles as staging area during compute
    __shared__ float sx_sh[K_PTS];
    __shared__ float sy_sh[K_PTS];
    __shared__ float u_sh[K_PTS];

    float* Xs = A;                          // [BK][XS_STRIDE] transposed tile of X
    float* Ys = A + BK * XS_STRIDE;         // [BK][XS_STRIDE] transposed tile of Y

    const float* Xg = X + (size_t)b * K_PTS * DIM;
    const float* Yg = Y + (size_t)b * K_PTS * DIM;

    // ---------------- Phase 1: cost matrix ----------------
    float acc[8][8];
#pragma unroll
    for (int i = 0; i < 8; ++i)
#pragma unroll
        for (int j = 0; j < 8; ++j) acc[i][j] = 0.0f;

    float nrm = 0.0f;                       // t<128: ||x_t||^2 ; t>=128: ||y_{t-128}||^2
    const int tx = t & 15;
    const int ty = t >> 4;

    for (int k0 = 0; k0 < DIM; k0 += BK) {
        __syncthreads();
        // stage BK columns of X and Y, transposed into LDS
#pragma unroll
        for (int i = 0; i < 4; ++i) {
            int idx = t + i * 256;          // 0..1023 ; 8 float4 per row of BK=32
            int r  = idx >> 3;
            int kq = idx & 7;
            float4 vx = *(const float4*)(Xg + r * DIM + k0 + kq * 4);
            float4 vy = *(const float4*)(Yg + r * DIM + k0 + kq * 4);
            int kb = kq * 4;
            Xs[(kb + 0) * XS_STRIDE + r] = vx.x;
            Xs[(kb + 1) * XS_STRIDE + r] = vx.y;
            Xs[(kb + 2) * XS_STRIDE + r] = vx.z;
            Xs[(kb + 3) * XS_STRIDE + r] = vx.w;
            Ys[(kb + 0) * XS_STRIDE + r] = vy.x;
            Ys[(kb + 1) * XS_STRIDE + r] = vy.y;
            Ys[(kb + 2) * XS_STRIDE + r] = vy.z;
            Ys[(kb + 3) * XS_STRIDE + r] = vy.w;
        }
        __syncthreads();
        // 8x8 outer-product accumulation
        for (int kk = 0; kk < BK; ++kk) {
            const float* xrow = Xs + kk * XS_STRIDE;
            const float* yrow = Ys + kk * XS_STRIDE;
            float4 xa = *(const float4*)(xrow + ty * 8);
            float4 xb = *(const float4*)(xrow + ty * 8 + 4);
            float4 ya = *(const float4*)(yrow + tx * 8);
            float4 yb = *(const float4*)(yrow + tx * 8 + 4);
            float av[8] = {xa.x, xa.y, xa.z, xa.w, xb.x, xb.y, xb.z, xb.w};
            float bv[8] = {ya.x, ya.y, ya.z, ya.w, yb.x, yb.y, yb.z, yb.w};
#pragma unroll
            for (int i = 0; i < 8; ++i)
#pragma unroll
                for (int j = 0; j < 8; ++j)
                    acc[i][j] = fmaf(av[i], bv[j], acc[i][j]);
        }
        // squared-norm partials (read back from LDS; conflict-free: consecutive lanes -> consecutive banks)
        if (t < 128) {
#pragma unroll
            for (int kk = 0; kk < BK; ++kk) {
                float v = Xs[kk * XS_STRIDE + t];
                nrm = fmaf(v, v, nrm);
            }
        } else {
#pragma unroll
            for (int kk = 0; kk < BK; ++kk) {
                float v = Ys[kk * XS_STRIDE + (t - 128)];
                nrm = fmaf(v, v, nrm);
            }
        }
    }
    if (t < 128) sx_sh[t] = nrm; else sy_sh[t - 128] = nrm;
    if (t < 128) u_sh[t] = 0.0f;
    __syncthreads();
    // epilogue: C[r][c] = ||x_r||^2 + ||y_c||^2 - 2*dot  (overwrites staging area)
#pragma unroll
    for (int i = 0; i < 8; ++i) {
        int r = ty * 8 + i;
        float sxr = sx_sh[r];
#pragma unroll
        for (int j = 0; j < 8; ++j) {
            int c = tx * 8 + j;
            A[r * K_PTS + c] = sxr + sy_sh[c] - 2.0f * acc[i][j];
        }
    }
    __syncthreads();

    // ---------------- Phase 2: LAP solve (wave 0 only, wave-synchronous) ----------------
    if (t < 64) {
        // lane owns columns t and t+64
        float v0 = 0.0f, v1 = 0.0f;         // column potentials
        int p_lo = -1, p_hi = -1;           // matched row per column (-1 = free)

        for (int row = 0; row < K_PTS; ++row) {
            float u_i = u_sh[row];
            float dist0 = fmaxf(A[row * K_PTS + t]      - u_i - v0, 0.0f);
            float dist1 = fmaxf(A[row * K_PTS + 64 + t] - u_i - v1, 0.0f);
            int way0 = 128, way1 = 128;     // 128 = sentinel (path start)
            bool sc0 = false, sc1 = false;  // scanned flags
            int j1 = 0;
            float D = 0.0f;

            while (true) {
                // packed argmin key: dist bits (nonneg float -> monotone u32), low 7 bits = column
                unsigned k0 = sc0 ? 0xFFFFFFFFu
                                  : ((__float_as_uint(dist0) & 0xFFFFFF80u) | (unsigned)t);
                unsigned k1 = sc1 ? 0xFFFFFFFFu
                                  : ((__float_as_uint(dist1) & 0xFFFFFF80u) | (unsigned)(t + 64));
                unsigned k = min(k0, k1);
#pragma unroll
                for (int m = 1; m <= 32; m <<= 1)
                    k = min(k, (unsigned)__shfl_xor((int)k, m, 64));
                j1 = (int)(k & 127u);
                int lane = j1 & 63;
                bool hi = j1 >= 64;                     // uniform
                D       = rdlane_f(hi ? dist1 : dist0, lane);  // exact min distance
                int i1  = rdlane_i(hi ? p_hi : p_lo, lane);
                if (i1 < 0) break;                      // reached a free column -> augment

                if (j1 == t)      sc0 = true;
                if (j1 == t + 64) sc1 = true;

                // relax from row i1 (original potentials; delta folded into D)
                float ui1 = u_sh[i1];
                float a0 = A[i1 * K_PTS + t];
                float a1 = A[i1 * K_PTS + 64 + t];
                float base = D - ui1;
                if (!sc0) {
                    float c0 = fmaxf((a0 - v0) + base, 0.0f);
                    if (c0 < dist0) { dist0 = c0; way0 = j1; }
                }
                if (!sc1) {
                    float c1 = fmaxf((a1 - v1) + base, 0.0f);
                    if (c1 < dist1) { dist1 = c1; way1 = j1; }
                }
            }

            // potential updates (once per row): for scanned j: v[j] -= (D - dist[j]); u[p[j]] += (D - dist[j])
            if (sc0) { float del = D - dist0; v0 -= del; u_sh[p_lo] += del; }
            if (sc1) { float del = D - dist1; v1 -= del; u_sh[p_hi] += del; }
            if (t == 0) u_sh[row] += D;

            // augment along alternating path (uniform walk via readlane)
            int j0 = j1;
            while (true) {
                int lane0 = j0 & 63;
                bool hi0 = j0 >= 64;                    // uniform
                int jp = rdlane_i(hi0 ? way1 : way0, lane0);
                int pv;
                if (jp == 128) pv = row;
                else           pv = rdlane_i((jp >= 64) ? p_hi : p_lo, jp & 63);
                if (!hi0 && j0 == t)      p_lo = pv;
                if ( hi0 && j0 == t + 64) p_hi = pv;
                if (jp == 128) break;
                j0 = jp;
            }
            // make u_sh scatter-writes visible to next row's reads (single wave: waitcnt + compiler fence)
            asm volatile("s_waitcnt lgkmcnt(0)" ::: "memory");
        }

        // total optimal cost for this batch: sum_j A[p[j]][j]
        float tsum = A[p_lo * K_PTS + t] + A[p_hi * K_PTS + 64 + t];
#pragma unroll
        for (int m = 1; m <= 32; m <<= 1)
            tsum += __shfl_xor(tsum, m, 64);
        if (t == 0) atomicAdd(out, tsum * inv_total);
    }
}

extern "C" void kernel_launch(void* const* d_in, const int* in_sizes, int n_in,
                              void* d_out, int out_size, void* d_ws, size_t ws_size,
                              hipStream_t stream) {
    const float* X = (const float*)d_in[0];
    const float* Y = (const float*)d_in[1];
    float* out = (float*)d_out;

    const int total = in_sizes[0];              // B*K*D
    const int B = total / (K_PTS * DIM);
    const float inv_total = 1.0f / (float)total;

    hipMemsetAsync(out, 0, out_size * sizeof(float), stream);
    hungarian_mse_kernel<<<dim3(B), dim3(256), 0, stream>>>(X, Y, out, inv_total);
}

// Round 2
// 838.388 us; speedup vs baseline: 1.7064x; 1.7064x over previous
//
#include <hip/hip_runtime.h>
#include <hip/hip_bf16.h>

#define K_PTS 128
#define DIM   512
#define BK    32
#define XS_STRIDE 132   // padded leading dim for transposed staging

__device__ __forceinline__ int rdlane_i(int v, int lane) {
    return __builtin_amdgcn_readlane(v, lane);
}
__device__ __forceinline__ float rdlane_f(float v, int lane) {
    return __int_as_float(__builtin_amdgcn_readlane(__float_as_int(v), lane));
}
__device__ __forceinline__ void wave_fence() {
    // single-wave LDS visibility: drain DS ops + compiler barrier
    asm volatile("s_waitcnt lgkmcnt(0)" ::: "memory");
}

// One block per batch: 128x128 squared-distance cost matrix in LDS, then
// Jonker-Volgenant LAP (column reduction + augmenting row reduction +
// shortest augmenting paths) on wave 0; atomicAdd optimal cost into *out.
__global__ __launch_bounds__(256, 2)
void hungarian_mse_kernel(const float* __restrict__ X, const float* __restrict__ Y,
                          float* __restrict__ out, float inv_total) {
    const int b = blockIdx.x;
    const int t = threadIdx.x;

    __shared__ float A[K_PTS * K_PTS];      // cost matrix; doubles as staging during compute
    __shared__ float sx_sh[K_PTS];
    __shared__ float sy_sh[K_PTS];
    __shared__ float u_sh[K_PTS];
    __shared__ int   rmatch[K_PTS];         // row -> column (or -1)
    __shared__ int   wl[512];               // worklist of free rows
    __shared__ int   wl_n;

    float* Xs = A;                          // [BK][XS_STRIDE] transposed tile of X
    float* Ys = A + BK * XS_STRIDE;         // [BK][XS_STRIDE] transposed tile of Y

    const float* Xg = X + (size_t)b * K_PTS * DIM;
    const float* Yg = Y + (size_t)b * K_PTS * DIM;

    // ---------------- Phase 1: cost matrix ----------------
    float acc[8][8];
#pragma unroll
    for (int i = 0; i < 8; ++i)
#pragma unroll
        for (int j = 0; j < 8; ++j) acc[i][j] = 0.0f;

    float nrm = 0.0f;
    const int tx = t & 15;
    const int ty = t >> 4;

    for (int k0 = 0; k0 < DIM; k0 += BK) {
        __syncthreads();
#pragma unroll
        for (int i = 0; i < 4; ++i) {
            int idx = t + i * 256;
            int r  = idx >> 3;
            int kq = idx & 7;
            float4 vx = *(const float4*)(Xg + r * DIM + k0 + kq * 4);
            float4 vy = *(const float4*)(Yg + r * DIM + k0 + kq * 4);
            int kb = kq * 4;
            Xs[(kb + 0) * XS_STRIDE + r] = vx.x;
            Xs[(kb + 1) * XS_STRIDE + r] = vx.y;
            Xs[(kb + 2) * XS_STRIDE + r] = vx.z;
            Xs[(kb + 3) * XS_STRIDE + r] = vx.w;
            Ys[(kb + 0) * XS_STRIDE + r] = vy.x;
            Ys[(kb + 1) * XS_STRIDE + r] = vy.y;
            Ys[(kb + 2) * XS_STRIDE + r] = vy.z;
            Ys[(kb + 3) * XS_STRIDE + r] = vy.w;
        }
        __syncthreads();
        for (int kk = 0; kk < BK; ++kk) {
            const float* xrow = Xs + kk * XS_STRIDE;
            const float* yrow = Ys + kk * XS_STRIDE;
            float4 xa = *(const float4*)(xrow + ty * 8);
            float4 xb = *(const float4*)(xrow + ty * 8 + 4);
            float4 ya = *(const float4*)(yrow + tx * 8);
            float4 yb = *(const float4*)(yrow + tx * 8 + 4);
            float av[8] = {xa.x, xa.y, xa.z, xa.w, xb.x, xb.y, xb.z, xb.w};
            float bv[8] = {ya.x, ya.y, ya.z, ya.w, yb.x, yb.y, yb.z, yb.w};
#pragma unroll
            for (int i = 0; i < 8; ++i)
#pragma unroll
                for (int j = 0; j < 8; ++j)
                    acc[i][j] = fmaf(av[i], bv[j], acc[i][j]);
        }
        if (t < 128) {
#pragma unroll
            for (int kk = 0; kk < BK; ++kk) {
                float v = Xs[kk * XS_STRIDE + t];
                nrm = fmaf(v, v, nrm);
            }
        } else {
#pragma unroll
            for (int kk = 0; kk < BK; ++kk) {
                float v = Ys[kk * XS_STRIDE + (t - 128)];
                nrm = fmaf(v, v, nrm);
            }
        }
    }
    if (t < 128) sx_sh[t] = nrm; else sy_sh[t - 128] = nrm;
    if (t < 128) u_sh[t] = 0.0f;
    __syncthreads();
#pragma unroll
    for (int i = 0; i < 8; ++i) {
        int r = ty * 8 + i;
        float sxr = sx_sh[r];
#pragma unroll
        for (int j = 0; j < 8; ++j) {
            int c = tx * 8 + j;
            A[r * K_PTS + c] = sxr + sy_sh[c] - 2.0f * acc[i][j];
        }
    }
    __syncthreads();

    // ---------------- Phase 2: LAP solve (wave 0, wave-synchronous) ----------------
    if (t < 64) {
        float v0, v1;                       // column potentials (lane owns cols t, t+64)
        int p_lo = -1, p_hi = -1;           // matched row per column (-1 = free)

        // --- A) column reduction: v[j] = min_i c[i][j]; greedy unique-argmin assign ---
        rmatch[t] = -1; rmatch[t + 64] = -1;
        wave_fence();
        {
            float m0 = 1e30f, m1 = 1e30f;
            int a0 = 0, a1 = 0;
#pragma unroll 4
            for (int i = 0; i < K_PTS; ++i) {
                float c0 = A[i * K_PTS + t];
                float c1 = A[i * K_PTS + 64 + t];
                if (c0 < m0) { m0 = c0; a0 = i; }
                if (c1 < m1) { m1 = c1; a1 = i; }
            }
            v0 = m0; v1 = m1;
            int w0 = atomicCAS(&rmatch[a0], -1, (int)t);
            if (w0 == -1) p_lo = a0;
            int w1 = atomicCAS(&rmatch[a1], -1, (int)(t + 64));
            if (w1 == -1) p_hi = a1;
        }
        wave_fence();

        // --- worklist of free rows ---
        if (t == 0) {
            int n = 0;
            for (int i = 0; i < K_PTS; ++i) if (rmatch[i] < 0) wl[n++] = i;
            wl_n = n;
        }
        wave_fence();

        // --- B) augmenting row reduction (capped) ---
        {
            int head = 0, tail = wl_n, steps = 0;
            while (head < tail && steps < 320) {
                ++steps;
                int i = wl[head++];
                float r0 = fmaxf(A[i * K_PTS + t]      - v0, 0.0f);
                float r1 = fmaxf(A[i * K_PTS + 64 + t] - v1, 0.0f);
                unsigned k0 = (__float_as_uint(r0) & 0xFFFFFF80u) | (unsigned)t;
                unsigned k1 = (__float_as_uint(r1) & 0xFFFFFF80u) | (unsigned)(t + 64);
                unsigned best = min(k0, k1), sec = max(k0, k1);
#pragma unroll
                for (int m = 1; m <= 16; m <<= 1) {
                    unsigned ob = (unsigned)__shfl_xor((int)best, m, 64);
                    unsigned os = (unsigned)__shfl_xor((int)sec,  m, 64);
                    unsigned nb = min(best, ob);
                    unsigned ns = min(max(best, ob), min(sec, os));
                    best = nb; sec = ns;
                }
                unsigned bl = (unsigned)rdlane_i((int)best, 0);
                unsigned bh = (unsigned)rdlane_i((int)best, 32);
                unsigned sl = (unsigned)rdlane_i((int)sec, 0);
                unsigned sh = (unsigned)rdlane_i((int)sec, 32);
                unsigned b2 = min(bl, bh);
                unsigned s2 = min(max(bl, bh), min(sl, sh));
                int j1 = (int)(b2 & 127u);
                int j2 = (int)(s2 & 127u);
                float mu = rdlane_f((j1 >= 64) ? r1 : r0, j1 & 63);
                float nu = rdlane_f((j2 >= 64) ? r1 : r0, j2 & 63);
                if (t == 0) u_sh[i] = nu;
                int kO = rdlane_i((j1 >= 64) ? p_hi : p_lo, j1 & 63);
                bool strict = (mu < nu);
                if (strict && t == (j1 & 63)) {
                    float d = nu - mu;
                    if (j1 >= 64) v1 -= d; else v0 -= d;
                }
                int jA = j1;
                if (!strict && kO >= 0) {
                    int k2 = rdlane_i((j2 >= 64) ? p_hi : p_lo, j2 & 63);
                    if (k2 < 0) jA = j2;
                }
                int kOld = rdlane_i((jA >= 64) ? p_hi : p_lo, jA & 63);
                if (t == (jA & 63)) { if (jA >= 64) p_hi = i; else p_lo = i; }
                if (t == 0) {
                    rmatch[i] = jA;
                    if (kOld >= 0) { rmatch[kOld] = -1; wl[tail] = kOld; }
                }
                if (kOld >= 0) ++tail;
                wave_fence();
            }
        }

        // --- rebuild free-row list (catches cap leftovers too) ---
        if (t == 0) {
            int n = 0;
            for (int i = 0; i < K_PTS; ++i) if (rmatch[i] < 0) wl[n++] = i;
            wl_n = n;
        }
        wave_fence();
        const int nfree = wl_n;

        // --- C) shortest augmenting path for remaining free rows ---
        for (int idx = 0; idx < nfree; ++idx) {
            int row = wl[idx];
            float u_i = u_sh[row];
            float dist0 = fmaxf(A[row * K_PTS + t]      - u_i - v0, 0.0f);
            float dist1 = fmaxf(A[row * K_PTS + 64 + t] - u_i - v1, 0.0f);
            int way0 = 128, way1 = 128;
            bool sc0 = false, sc1 = false;
            int j1 = 0;
            float D = 0.0f;

            while (true) {
                unsigned k0 = sc0 ? 0xFFFFFFFFu
                                  : ((__float_as_uint(dist0) & 0xFFFFFF80u) | (unsigned)t);
                unsigned k1 = sc1 ? 0xFFFFFFFFu
                                  : ((__float_as_uint(dist1) & 0xFFFFFF80u) | (unsigned)(t + 64));
                unsigned k = min(k0, k1);
#pragma unroll
                for (int m = 1; m <= 16; m <<= 1)
                    k = min(k, (unsigned)__shfl_xor((int)k, m, 64));
                unsigned kl = (unsigned)rdlane_i((int)k, 0);
                unsigned kh = (unsigned)rdlane_i((int)k, 32);
                k = min(kl, kh);
                j1 = (int)(k & 127u);
                int lane = j1 & 63;
                bool hi = j1 >= 64;
                D       = rdlane_f(hi ? dist1 : dist0, lane);
                int i1  = rdlane_i(hi ? p_hi : p_lo, lane);
                if (i1 < 0) break;

                if (j1 == t)      sc0 = true;
                if (j1 == t + 64) sc1 = true;

                float ui1 = u_sh[i1];
                float a0 = A[i1 * K_PTS + t];
                float a1 = A[i1 * K_PTS + 64 + t];
                float base = D - ui1;
                if (!sc0) {
                    float c0 = fmaxf((a0 - v0) + base, 0.0f);
                    if (c0 < dist0) { dist0 = c0; way0 = j1; }
                }
                if (!sc1) {
                    float c1 = fmaxf((a1 - v1) + base, 0.0f);
                    if (c1 < dist1) { dist1 = c1; way1 = j1; }
                }
            }

            if (sc0) { float del = D - dist0; v0 -= del; u_sh[p_lo] += del; }
            if (sc1) { float del = D - dist1; v1 -= del; u_sh[p_hi] += del; }
            if (t == 0) u_sh[row] += D;

            int j0 = j1;
            while (true) {
                int lane0 = j0 & 63;
                bool hi0 = j0 >= 64;
                int jp = rdlane_i(hi0 ? way1 : way0, lane0);
                int pv;
                if (jp == 128) pv = row;
                else           pv = rdlane_i((jp >= 64) ? p_hi : p_lo, jp & 63);
                if (!hi0 && j0 == t)      p_lo = pv;
                if ( hi0 && j0 == t + 64) p_hi = pv;
                if (jp == 128) break;
                j0 = jp;
            }
            wave_fence();
        }

        // --- total optimal cost for this batch ---
        float tsum = A[p_lo * K_PTS + t] + A[p_hi * K_PTS + 64 + t];
#pragma unroll
        for (int m = 1; m <= 32; m <<= 1)
            tsum += __shfl_xor(tsum, m, 64);
        if (t == 0) atomicAdd(out, tsum * inv_total);
    }
}

extern "C" void kernel_launch(void* const* d_in, const int* in_sizes, int n_in,
                              void* d_out, int out_size, void* d_ws, size_t ws_size,
                              hipStream_t stream) {
    const float* X = (const float*)d_in[0];
    const float* Y = (const float*)d_in[1];
    float* out = (float*)d_out;

    const int total = in_sizes[0];              // B*K*D
    const int B = total / (K_PTS * DIM);
    const float inv_total = 1.0f / (float)total;

    hipMemsetAsync(out, 0, out_size * sizeof(float), stream);
    hungarian_mse_kernel<<<dim3(B), dim3(256), 0, stream>>>(X, Y, out, inv_total);
}

// Round 3
// 687.960 us; speedup vs baseline: 2.0795x; 1.2187x over previous
//
#include <hip/hip_runtime.h>
#include <hip/hip_bf16.h>

#define K_PTS 128
#define DIM   512
#define BK    32
#define XS_STRIDE 132   // padded leading dim for transposed staging

__device__ __forceinline__ int rdlane_i(int v, int lane) {
    return __builtin_amdgcn_readlane(v, lane);
}
__device__ __forceinline__ float rdlane_f(float v, int lane) {
    return __int_as_float(__builtin_amdgcn_readlane(__float_as_int(v), lane));
}
__device__ __forceinline__ void wave_fence() {
    asm volatile("s_waitcnt lgkmcnt(0)" ::: "memory");
}

#define DPP_ID 0xFFFFFFFFu

template <int CTRL, int RM>
__device__ __forceinline__ unsigned dpp_min1(unsigned k) {
    unsigned o = (unsigned)__builtin_amdgcn_update_dpp((int)DPP_ID, (int)k, CTRL, RM, 0xF, false);
    return min(k, o);
}
// min over 64 lanes -> uniform (via lane 63)
__device__ __forceinline__ unsigned wave_min_u32(unsigned k) {
    k = dpp_min1<0x111, 0xF>(k);   // row_shr:1
    k = dpp_min1<0x112, 0xF>(k);   // row_shr:2
    k = dpp_min1<0x114, 0xF>(k);   // row_shr:4
    k = dpp_min1<0x118, 0xF>(k);   // row_shr:8
    k = dpp_min1<0x142, 0xA>(k);   // row_bcast:15 -> rows 1,3
    k = dpp_min1<0x143, 0xC>(k);   // row_bcast:31 -> rows 2,3
    return (unsigned)rdlane_i((int)k, 63);
}
template <int CTRL, int RM>
__device__ __forceinline__ void dpp_min2(unsigned& best, unsigned& sec) {
    unsigned ob = (unsigned)__builtin_amdgcn_update_dpp((int)DPP_ID, (int)best, CTRL, RM, 0xF, false);
    unsigned os = (unsigned)__builtin_amdgcn_update_dpp((int)DPP_ID, (int)sec,  CTRL, RM, 0xF, false);
    sec  = min(max(best, ob), min(sec, os));
    best = min(best, ob);
}
// (min, 2nd-min) over 64 lanes -> uniform pair
__device__ __forceinline__ void wave_min2_u32(unsigned& best, unsigned& sec) {
    dpp_min2<0x111, 0xF>(best, sec);
    dpp_min2<0x112, 0xF>(best, sec);
    dpp_min2<0x114, 0xF>(best, sec);
    dpp_min2<0x118, 0xF>(best, sec);
    dpp_min2<0x142, 0xA>(best, sec);
    dpp_min2<0x143, 0xC>(best, sec);
    best = (unsigned)rdlane_i((int)best, 63);
    sec  = (unsigned)rdlane_i((int)sec, 63);
}

// One block per batch: 128x128 squared-distance cost matrix in LDS, then
// LAPJV (column reduction + reduction transfer + augmenting row reduction +
// shortest augmenting paths) on wave 0; atomicAdd optimal cost into *out.
__global__ __launch_bounds__(256, 2)
void hungarian_mse_kernel(const float* __restrict__ X, const float* __restrict__ Y,
                          float* __restrict__ out, float inv_total) {
    const int b = blockIdx.x;
    const int t = threadIdx.x;

    __shared__ float A[K_PTS * K_PTS];      // cost matrix; doubles as staging during compute
    __shared__ float sx_sh[K_PTS];          // later: mu per row (transfer)
    __shared__ float sy_sh[K_PTS];          // later: v_sh (transfer scan)
    __shared__ float u_sh[K_PTS];
    __shared__ int   rmatch[K_PTS];         // row -> column (or -1)
    __shared__ int   wl[512];               // worklist of free rows
    __shared__ int   wl_n;

    float* Xs = A;                          // [BK][XS_STRIDE] transposed tile of X
    float* Ys = A + BK * XS_STRIDE;         // [BK][XS_STRIDE] transposed tile of Y

    const float* Xg = X + (size_t)b * K_PTS * DIM;
    const float* Yg = Y + (size_t)b * K_PTS * DIM;

    // ---------------- Phase 1: cost matrix ----------------
    float acc[8][8];
#pragma unroll
    for (int i = 0; i < 8; ++i)
#pragma unroll
        for (int j = 0; j < 8; ++j) acc[i][j] = 0.0f;

    float nrm = 0.0f;
    const int tx = t & 15;
    const int ty = t >> 4;

    for (int k0 = 0; k0 < DIM; k0 += BK) {
        __syncthreads();
#pragma unroll
        for (int i = 0; i < 4; ++i) {
            int idx = t + i * 256;
            int r  = idx >> 3;
            int kq = idx & 7;
            float4 vx = *(const float4*)(Xg + r * DIM + k0 + kq * 4);
            float4 vy = *(const float4*)(Yg + r * DIM + k0 + kq * 4);
            int kb = kq * 4;
            Xs[(kb + 0) * XS_STRIDE + r] = vx.x;
            Xs[(kb + 1) * XS_STRIDE + r] = vx.y;
            Xs[(kb + 2) * XS_STRIDE + r] = vx.z;
            Xs[(kb + 3) * XS_STRIDE + r] = vx.w;
            Ys[(kb + 0) * XS_STRIDE + r] = vy.x;
            Ys[(kb + 1) * XS_STRIDE + r] = vy.y;
            Ys[(kb + 2) * XS_STRIDE + r] = vy.z;
            Ys[(kb + 3) * XS_STRIDE + r] = vy.w;
        }
        __syncthreads();
        for (int kk = 0; kk < BK; ++kk) {
            const float* xrow = Xs + kk * XS_STRIDE;
            const float* yrow = Ys + kk * XS_STRIDE;
            float4 xa = *(const float4*)(xrow + ty * 8);
            float4 xb = *(const float4*)(xrow + ty * 8 + 4);
            float4 ya = *(const float4*)(yrow + tx * 8);
            float4 yb = *(const float4*)(yrow + tx * 8 + 4);
            float av[8] = {xa.x, xa.y, xa.z, xa.w, xb.x, xb.y, xb.z, xb.w};
            float bv[8] = {ya.x, ya.y, ya.z, ya.w, yb.x, yb.y, yb.z, yb.w};
#pragma unroll
            for (int i = 0; i < 8; ++i)
#pragma unroll
                for (int j = 0; j < 8; ++j)
                    acc[i][j] = fmaf(av[i], bv[j], acc[i][j]);
        }
        if (t < 128) {
#pragma unroll
            for (int kk = 0; kk < BK; ++kk) {
                float v = Xs[kk * XS_STRIDE + t];
                nrm = fmaf(v, v, nrm);
            }
        } else {
#pragma unroll
            for (int kk = 0; kk < BK; ++kk) {
                float v = Ys[kk * XS_STRIDE + (t - 128)];
                nrm = fmaf(v, v, nrm);
            }
        }
    }
    if (t < 128) sx_sh[t] = nrm; else sy_sh[t - 128] = nrm;
    if (t < 128) u_sh[t] = 0.0f;
    __syncthreads();
#pragma unroll
    for (int i = 0; i < 8; ++i) {
        int r = ty * 8 + i;
        float sxr = sx_sh[r];
#pragma unroll
        for (int j = 0; j < 8; ++j) {
            int c = tx * 8 + j;
            A[r * K_PTS + c] = sxr + sy_sh[c] - 2.0f * acc[i][j];
        }
    }
    __syncthreads();

    // ---------------- Phase 2: LAP solve (wave 0, wave-synchronous) ----------------
    if (t < 64) {
        asm volatile("s_setprio 3");        // win VALU arbitration vs co-resident GEMM waves
        float v0, v1;                       // column potentials (lane owns cols t, t+64)
        int p_lo = -1, p_hi = -1;           // matched row per column (-1 = free)

        // --- A) column reduction: v[j] = min_i c[i][j]; greedy unique-argmin assign ---
        rmatch[t] = -1; rmatch[t + 64] = -1;
        wave_fence();
        {
            float m0 = 1e30f, m1 = 1e30f;
            int a0 = 0, a1 = 0;
#pragma unroll 4
            for (int i = 0; i < K_PTS; ++i) {
                float c0 = A[i * K_PTS + t];
                float c1 = A[i * K_PTS + 64 + t];
                if (c0 < m0) { m0 = c0; a0 = i; }
                if (c1 < m1) { m1 = c1; a1 = i; }
            }
            v0 = m0; v1 = m1;
            int w0 = atomicCAS(&rmatch[a0], -1, (int)t);
            if (w0 == -1) p_lo = a0;
            int w1 = atomicCAS(&rmatch[a1], -1, (int)(t + 64));
            if (w1 == -1) p_hi = a1;
        }
        wave_fence();

        // --- A2) reduction transfer (parallel over rows; stale-v is feasibility-safe) ---
        sy_sh[t] = v0; sy_sh[t + 64] = v1;      // v snapshot for row scans
        wave_fence();
#pragma unroll
        for (int which = 0; which < 2; ++which) {
            int i  = t + which * 64;
            int j1 = rmatch[i];
            float mu = 1e30f;
            if (j1 >= 0) {
#pragma unroll 4
                for (int s = 0; s < K_PTS; ++s) {
                    int jj = (s + t) & 127;     // diagonal stagger: conflict-free
                    float rc = A[i * K_PTS + jj] - sy_sh[jj];
                    if (jj != j1) mu = fminf(mu, rc);
                }
            }
            sx_sh[i] = mu;
        }
        wave_fence();
        if (p_lo >= 0) { float mu = sx_sh[p_lo]; v0 = A[p_lo * K_PTS + t]      - mu; u_sh[p_lo] = mu; }
        if (p_hi >= 0) { float mu = sx_sh[p_hi]; v1 = A[p_hi * K_PTS + 64 + t] - mu; u_sh[p_hi] = mu; }
        wave_fence();

        // --- worklist of free rows ---
        if (t == 0) {
            int n = 0;
            for (int i = 0; i < K_PTS; ++i) if (rmatch[i] < 0) wl[n++] = i;
            wl_n = n;
        }
        wave_fence();

        // --- B) augmenting row reduction (capped) ---
        {
            int head = 0, tail = wl_n, steps = 0;
            while (head < tail && steps < 320) {
                ++steps;
                int i = wl[head++];
                float r0 = fmaxf(A[i * K_PTS + t]      - v0, 0.0f);
                float r1 = fmaxf(A[i * K_PTS + 64 + t] - v1, 0.0f);
                unsigned k0 = (__float_as_uint(r0) & 0xFFFFFF80u) | (unsigned)t;
                unsigned k1 = (__float_as_uint(r1) & 0xFFFFFF80u) | (unsigned)(t + 64);
                unsigned best = min(k0, k1), sec = max(k0, k1);
                wave_min2_u32(best, sec);
                int j1 = (int)(best & 127u);
                int j2 = (int)(sec & 127u);
                float mu = rdlane_f((j1 >= 64) ? r1 : r0, j1 & 63);
                float nu = rdlane_f((j2 >= 64) ? r1 : r0, j2 & 63);
                if (t == 0) u_sh[i] = nu;
                int kO = rdlane_i((j1 >= 64) ? p_hi : p_lo, j1 & 63);
                bool strict = (mu < nu);
                if (strict && t == (j1 & 63)) {
                    float d = nu - mu;
                    if (j1 >= 64) v1 -= d; else v0 -= d;
                }
                int jA = j1;
                if (!strict && kO >= 0) {
                    int k2 = rdlane_i((j2 >= 64) ? p_hi : p_lo, j2 & 63);
                    if (k2 < 0) jA = j2;
                }
                int kOld = rdlane_i((jA >= 64) ? p_hi : p_lo, jA & 63);
                if (t == (jA & 63)) { if (jA >= 64) p_hi = i; else p_lo = i; }
                if (t == 0) {
                    rmatch[i] = jA;
                    if (kOld >= 0) { rmatch[kOld] = -1; wl[tail] = kOld; }
                }
                if (kOld >= 0) ++tail;
                wave_fence();
            }
        }

        // --- rebuild free-row list (catches cap leftovers too) ---
        if (t == 0) {
            int n = 0;
            for (int i = 0; i < K_PTS; ++i) if (rmatch[i] < 0) wl[n++] = i;
            wl_n = n;
        }
        wave_fence();
        const int nfree = wl_n;

        // --- C) shortest augmenting path for remaining free rows ---
        for (int idx = 0; idx < nfree; ++idx) {
            int row = wl[idx];
            float u_i = u_sh[row];
            float dist0 = fmaxf(A[row * K_PTS + t]      - u_i - v0, 0.0f);
            float dist1 = fmaxf(A[row * K_PTS + 64 + t] - u_i - v1, 0.0f);
            int way0 = 128, way1 = 128;
            bool sc0 = false, sc1 = false;
            int j1 = 0;
            float D = 0.0f;

            while (true) {
                unsigned k0 = sc0 ? 0xFFFFFFFFu
                                  : ((__float_as_uint(dist0) & 0xFFFFFF80u) | (unsigned)t);
                unsigned k1 = sc1 ? 0xFFFFFFFFu
                                  : ((__float_as_uint(dist1) & 0xFFFFFF80u) | (unsigned)(t + 64));
                unsigned k = wave_min_u32(min(k0, k1));
                j1 = (int)(k & 127u);
                int lane = j1 & 63;
                bool hi = j1 >= 64;
                D       = rdlane_f(hi ? dist1 : dist0, lane);
                int i1  = rdlane_i(hi ? p_hi : p_lo, lane);
                if (i1 < 0) break;

                if (j1 == t)      sc0 = true;
                if (j1 == t + 64) sc1 = true;

                float ui1 = u_sh[i1];
                float a0 = A[i1 * K_PTS + t];
                float a1 = A[i1 * K_PTS + 64 + t];
                float base = D - ui1;
                if (!sc0) {
                    float c0 = fmaxf((a0 - v0) + base, 0.0f);
                    if (c0 < dist0) { dist0 = c0; way0 = j1; }
                }
                if (!sc1) {
                    float c1 = fmaxf((a1 - v1) + base, 0.0f);
                    if (c1 < dist1) { dist1 = c1; way1 = j1; }
                }
            }

            if (sc0) { float del = D - dist0; v0 -= del; u_sh[p_lo] += del; }
            if (sc1) { float del = D - dist1; v1 -= del; u_sh[p_hi] += del; }
            if (t == 0) u_sh[row] += D;

            int j0 = j1;
            while (true) {
                int lane0 = j0 & 63;
                bool hi0 = j0 >= 64;
                int jp = rdlane_i(hi0 ? way1 : way0, lane0);
                int pv;
                if (jp == 128) pv = row;
                else           pv = rdlane_i((jp >= 64) ? p_hi : p_lo, jp & 63);
                if (!hi0 && j0 == t)      p_lo = pv;
                if ( hi0 && j0 == t + 64) p_hi = pv;
                if (jp == 128) break;
                j0 = jp;
            }
            wave_fence();
        }

        // --- total optimal cost for this batch ---
        float tsum = A[p_lo * K_PTS + t] + A[p_hi * K_PTS + 64 + t];
#pragma unroll
        for (int m = 1; m <= 32; m <<= 1)
            tsum += __shfl_xor(tsum, m, 64);
        if (t == 0) atomicAdd(out, tsum * inv_total);
    }
}

extern "C" void kernel_launch(void* const* d_in, const int* in_sizes, int n_in,
                              void* d_out, int out_size, void* d_ws, size_t ws_size,
                              hipStream_t stream) {
    const float* X = (const float*)d_in[0];
    const float* Y = (const float*)d_in[1];
    float* out = (float*)d_out;

    const int total = in_sizes[0];              // B*K*D
    const int B = total / (K_PTS * DIM);
    const float inv_total = 1.0f / (float)total;

    hipMemsetAsync(out, 0, out_size * sizeof(float), stream);
    hungarian_mse_kernel<<<dim3(B), dim3(256), 0, stream>>>(X, Y, out, inv_total);
}

// Round 4
// 680.556 us; speedup vs baseline: 2.1021x; 1.0109x over previous
//
#include <hip/hip_runtime.h>
#include <hip/hip_bf16.h>

#define K_PTS 128
#define DIM   512
#define BK    32
#define XS_STRIDE 132   // padded leading dim for transposed staging

__device__ __forceinline__ int rdlane_i(int v, int lane) {
    return __builtin_amdgcn_readlane(v, lane);
}
__device__ __forceinline__ float rdlane_f(float v, int lane) {
    return __int_as_float(__builtin_amdgcn_readlane(__float_as_int(v), lane));
}
__device__ __forceinline__ void wave_fence() {
    asm volatile("s_waitcnt lgkmcnt(0)" ::: "memory");
}

#define DPP_ID 0xFFFFFFFFu

template <int CTRL, int RM>
__device__ __forceinline__ unsigned dpp_min1(unsigned k) {
    unsigned o = (unsigned)__builtin_amdgcn_update_dpp((int)DPP_ID, (int)k, CTRL, RM, 0xF, false);
    return min(k, o);
}
// min over 64 lanes -> uniform (via lane 63)
__device__ __forceinline__ unsigned wave_min_u32(unsigned k) {
    k = dpp_min1<0x111, 0xF>(k);   // row_shr:1
    k = dpp_min1<0x112, 0xF>(k);   // row_shr:2
    k = dpp_min1<0x114, 0xF>(k);   // row_shr:4
    k = dpp_min1<0x118, 0xF>(k);   // row_shr:8
    k = dpp_min1<0x142, 0xA>(k);   // row_bcast:15 -> rows 1,3
    k = dpp_min1<0x143, 0xC>(k);   // row_bcast:31 -> rows 2,3
    return (unsigned)rdlane_i((int)k, 63);
}
template <int CTRL, int RM>
__device__ __forceinline__ void dpp_min2(unsigned& best, unsigned& sec) {
    unsigned ob = (unsigned)__builtin_amdgcn_update_dpp((int)DPP_ID, (int)best, CTRL, RM, 0xF, false);
    unsigned os = (unsigned)__builtin_amdgcn_update_dpp((int)DPP_ID, (int)sec,  CTRL, RM, 0xF, false);
    sec  = min(max(best, ob), min(sec, os));
    best = min(best, ob);
}
// (min, 2nd-min) over 64 lanes -> uniform pair
__device__ __forceinline__ void wave_min2_u32(unsigned& best, unsigned& sec) {
    dpp_min2<0x111, 0xF>(best, sec);
    dpp_min2<0x112, 0xF>(best, sec);
    dpp_min2<0x114, 0xF>(best, sec);
    dpp_min2<0x118, 0xF>(best, sec);
    dpp_min2<0x142, 0xA>(best, sec);
    dpp_min2<0x143, 0xC>(best, sec);
    best = (unsigned)rdlane_i((int)best, 63);
    sec  = (unsigned)rdlane_i((int)sec, 63);
}

// One block per batch: 128x128 squared-distance cost matrix in LDS, then
// LAPJV (column reduction + reduction transfer + augmenting row reduction +
// shortest augmenting paths) on wave 0; atomicAdd optimal cost into *out.
// Lane l owns COLUMN PAIR (2l, 2l+1) -> all row accesses are ds_read_b64.
__global__ __launch_bounds__(256, 2)
void hungarian_mse_kernel(const float* __restrict__ X, const float* __restrict__ Y,
                          float* __restrict__ out, float inv_total) {
    const int b = blockIdx.x;
    const int t = threadIdx.x;

    __shared__ float A[K_PTS * K_PTS];      // cost matrix; doubles as staging during compute
    __shared__ float sx_sh[K_PTS];          // later: mu per row (transfer)
    __shared__ float sy_sh[K_PTS];          // later: v snapshot (transfer scan)
    __shared__ float u_sh[K_PTS];
    __shared__ int   rmatch[K_PTS];         // row -> column (or -1)
    __shared__ int   wl[512];               // worklist of free rows
    __shared__ int   wl_n;

    float* Xs = A;                          // [BK][XS_STRIDE] transposed tile of X
    float* Ys = A + BK * XS_STRIDE;         // [BK][XS_STRIDE] transposed tile of Y

    const float* Xg = X + (size_t)b * K_PTS * DIM;
    const float* Yg = Y + (size_t)b * K_PTS * DIM;

    // ---------------- Phase 1: cost matrix ----------------
    float acc[8][8];
#pragma unroll
    for (int i = 0; i < 8; ++i)
#pragma unroll
        for (int j = 0; j < 8; ++j) acc[i][j] = 0.0f;

    float nrm = 0.0f;
    const int tx = t & 15;
    const int ty = t >> 4;

    for (int k0 = 0; k0 < DIM; k0 += BK) {
        __syncthreads();
#pragma unroll
        for (int i = 0; i < 4; ++i) {
            int idx = t + i * 256;
            int r  = idx >> 3;
            int kq = idx & 7;
            float4 vx = *(const float4*)(Xg + r * DIM + k0 + kq * 4);
            float4 vy = *(const float4*)(Yg + r * DIM + k0 + kq * 4);
            int kb = kq * 4;
            Xs[(kb + 0) * XS_STRIDE + r] = vx.x;
            Xs[(kb + 1) * XS_STRIDE + r] = vx.y;
            Xs[(kb + 2) * XS_STRIDE + r] = vx.z;
            Xs[(kb + 3) * XS_STRIDE + r] = vx.w;
            Ys[(kb + 0) * XS_STRIDE + r] = vy.x;
            Ys[(kb + 1) * XS_STRIDE + r] = vy.y;
            Ys[(kb + 2) * XS_STRIDE + r] = vy.z;
            Ys[(kb + 3) * XS_STRIDE + r] = vy.w;
        }
        __syncthreads();
        for (int kk = 0; kk < BK; ++kk) {
            const float* xrow = Xs + kk * XS_STRIDE;
            const float* yrow = Ys + kk * XS_STRIDE;
            float4 xa = *(const float4*)(xrow + ty * 8);
            float4 xb = *(const float4*)(xrow + ty * 8 + 4);
            float4 ya = *(const float4*)(yrow + tx * 8);
            float4 yb = *(const float4*)(yrow + tx * 8 + 4);
            float av[8] = {xa.x, xa.y, xa.z, xa.w, xb.x, xb.y, xb.z, xb.w};
            float bv[8] = {ya.x, ya.y, ya.z, ya.w, yb.x, yb.y, yb.z, yb.w};
#pragma unroll
            for (int i = 0; i < 8; ++i)
#pragma unroll
                for (int j = 0; j < 8; ++j)
                    acc[i][j] = fmaf(av[i], bv[j], acc[i][j]);
        }
        if (t < 128) {
#pragma unroll
            for (int kk = 0; kk < BK; ++kk) {
                float v = Xs[kk * XS_STRIDE + t];
                nrm = fmaf(v, v, nrm);
            }
        } else {
#pragma unroll
            for (int kk = 0; kk < BK; ++kk) {
                float v = Ys[kk * XS_STRIDE + (t - 128)];
                nrm = fmaf(v, v, nrm);
            }
        }
    }
    if (t < 128) sx_sh[t] = nrm; else sy_sh[t - 128] = nrm;
    if (t < 128) u_sh[t] = 0.0f;
    __syncthreads();
#pragma unroll
    for (int i = 0; i < 8; ++i) {
        int r = ty * 8 + i;
        float sxr = sx_sh[r];
        float4 o0, o1;
        o0.x = sxr + sy_sh[tx * 8 + 0] - 2.0f * acc[i][0];
        o0.y = sxr + sy_sh[tx * 8 + 1] - 2.0f * acc[i][1];
        o0.z = sxr + sy_sh[tx * 8 + 2] - 2.0f * acc[i][2];
        o0.w = sxr + sy_sh[tx * 8 + 3] - 2.0f * acc[i][3];
        o1.x = sxr + sy_sh[tx * 8 + 4] - 2.0f * acc[i][4];
        o1.y = sxr + sy_sh[tx * 8 + 5] - 2.0f * acc[i][5];
        o1.z = sxr + sy_sh[tx * 8 + 6] - 2.0f * acc[i][6];
        o1.w = sxr + sy_sh[tx * 8 + 7] - 2.0f * acc[i][7];
        *(float4*)&A[r * K_PTS + tx * 8]     = o0;
        *(float4*)&A[r * K_PTS + tx * 8 + 4] = o1;
    }
    __syncthreads();

    // ---------------- Phase 2: LAP solve (wave 0, wave-synchronous) ----------------
    if (t < 64) {
        asm volatile("s_setprio 3");        // win VALU arbitration vs co-resident GEMM waves
        const int c0 = 2 * t, c1 = 2 * t + 1;
        float v0, v1;                       // column potentials (lane owns cols 2t, 2t+1)
        int p_lo = -1, p_hi = -1;           // matched row per column (-1 = free)

        // --- A) column reduction: v[j] = min_i c[i][j]; greedy unique-argmin assign ---
        rmatch[t] = -1; rmatch[t + 64] = -1;
        wave_fence();
        {
            float m0 = 1e30f, m1 = 1e30f;
            int a0 = 0, a1 = 0;
#pragma unroll 4
            for (int i = 0; i < K_PTS; ++i) {
                float2 cc = *(const float2*)&A[i * K_PTS + c0];
                if (cc.x < m0) { m0 = cc.x; a0 = i; }
                if (cc.y < m1) { m1 = cc.y; a1 = i; }
            }
            v0 = m0; v1 = m1;
            int w0 = atomicCAS(&rmatch[a0], -1, c0);
            if (w0 == -1) p_lo = a0;
            int w1 = atomicCAS(&rmatch[a1], -1, c1);
            if (w1 == -1) p_hi = a1;
        }
        wave_fence();

        // --- A2) reduction transfer (parallel over rows; stale-v is feasibility-safe) ---
        *(float2*)&sy_sh[c0] = make_float2(v0, v1);
        wave_fence();
#pragma unroll
        for (int which = 0; which < 2; ++which) {
            int i  = t + which * 64;
            int j1 = rmatch[i];
            float mu = 1e30f;
            if (j1 >= 0) {
#pragma unroll 4
                for (int s = 0; s < 64; ++s) {
                    int jj = (s + t) & 63;          // pair index; diagonal stagger
                    float2 cc = *(const float2*)&A[i * K_PTS + 2 * jj];
                    float2 vv = *(const float2*)&sy_sh[2 * jj];
                    float r0 = cc.x - vv.x;
                    float r1 = cc.y - vv.y;
                    if (2 * jj     != j1) mu = fminf(mu, r0);
                    if (2 * jj + 1 != j1) mu = fminf(mu, r1);
                }
            }
            sx_sh[i] = mu;
        }
        wave_fence();
        if (p_lo >= 0) { float mu = sx_sh[p_lo]; v0 = A[p_lo * K_PTS + c0] - mu; u_sh[p_lo] = mu; }
        if (p_hi >= 0) { float mu = sx_sh[p_hi]; v1 = A[p_hi * K_PTS + c1] - mu; u_sh[p_hi] = mu; }
        wave_fence();

        // --- worklist of free rows ---
        if (t == 0) {
            int n = 0;
            for (int i = 0; i < K_PTS; ++i) if (rmatch[i] < 0) wl[n++] = i;
            wl_n = n;
        }
        wave_fence();

        // --- B) augmenting row reduction (capped) ---
        {
            int head = 0, tail = wl_n, steps = 0;
            while (head < tail && steps < 320) {
                ++steps;
                int i = wl[head++];
                float2 cc = *(const float2*)&A[i * K_PTS + c0];
                float r0 = fmaxf(cc.x - v0, 0.0f);
                float r1 = fmaxf(cc.y - v1, 0.0f);
                unsigned k0 = (__float_as_uint(r0) & 0xFFFFFF80u) | (unsigned)c0;
                unsigned k1 = (__float_as_uint(r1) & 0xFFFFFF80u) | (unsigned)c1;
                unsigned best = min(k0, k1), sec = max(k0, k1);
                wave_min2_u32(best, sec);
                int j1 = (int)(best & 127u);
                int j2 = (int)(sec & 127u);
                float mu = __uint_as_float(best & 0xFFFFFF80u);   // 128-ulp truncation: within tolerance
                float nu = __uint_as_float(sec  & 0xFFFFFF80u);
                if (t == 0) u_sh[i] = nu;
                int kO = rdlane_i((j1 & 1) ? p_hi : p_lo, j1 >> 1);
                bool strict = (mu < nu);
                if (strict && t == (j1 >> 1)) {
                    float d = nu - mu;
                    if (j1 & 1) v1 -= d; else v0 -= d;
                }
                int jA = j1;
                if (!strict && kO >= 0) {
                    int k2 = rdlane_i((j2 & 1) ? p_hi : p_lo, j2 >> 1);
                    if (k2 < 0) jA = j2;
                }
                int kOld = rdlane_i((jA & 1) ? p_hi : p_lo, jA >> 1);
                if (t == (jA >> 1)) { if (jA & 1) p_hi = i; else p_lo = i; }
                if (t == 0) {
                    rmatch[i] = jA;
                    if (kOld >= 0) { rmatch[kOld] = -1; wl[tail] = kOld; }
                }
                if (kOld >= 0) ++tail;
                wave_fence();
            }
        }

        // --- rebuild free-row list (catches cap leftovers too) ---
        if (t == 0) {
            int n = 0;
            for (int i = 0; i < K_PTS; ++i) if (rmatch[i] < 0) wl[n++] = i;
            wl_n = n;
        }
        wave_fence();
        const int nfree = wl_n;

        // --- C) shortest augmenting path for remaining free rows ---
        for (int idx = 0; idx < nfree; ++idx) {
            int row = wl[idx];
            // u[] cached in wave registers for this search (u constant inside the loop)
            float u_lo_reg = u_sh[t];
            float u_hi_reg = u_sh[t + 64];
            float u_row = rdlane_f((row >= 64) ? u_hi_reg : u_lo_reg, row & 63);
            float2 rc = *(const float2*)&A[row * K_PTS + c0];
            float dist0 = fmaxf(rc.x - u_row - v0, 0.0f);
            float dist1 = fmaxf(rc.y - u_row - v1, 0.0f);
            int way0 = 128, way1 = 128;
            bool sc0 = false, sc1 = false;
            int j1 = 0;
            float D = 0.0f;

            while (true) {
                unsigned k0 = sc0 ? 0xFFFFFFFFu
                                  : ((__float_as_uint(dist0) & 0xFFFFFF80u) | (unsigned)c0);
                unsigned k1 = sc1 ? 0xFFFFFFFFu
                                  : ((__float_as_uint(dist1) & 0xFFFFFF80u) | (unsigned)c1);
                unsigned k = wave_min_u32(min(k0, k1));
                j1 = (int)(k & 127u);
                D  = __uint_as_float(k & 0xFFFFFF80u);  // truncated min-dist (no readlane)
                int i1 = rdlane_i((j1 & 1) ? p_hi : p_lo, j1 >> 1);
                if (i1 < 0) break;

                if (j1 == c0) sc0 = true;
                if (j1 == c1) sc1 = true;

                float u_i1 = rdlane_f((i1 >= 64) ? u_hi_reg : u_lo_reg, i1 & 63);
                float2 aa = *(const float2*)&A[i1 * K_PTS + c0];
                float base = D - u_i1;
                if (!sc0) {
                    float cv = fmaxf((aa.x - v0) + base, 0.0f);
                    if (cv < dist0) { dist0 = cv; way0 = j1; }
                }
                if (!sc1) {
                    float cv = fmaxf((aa.y - v1) + base, 0.0f);
                    if (cv < dist1) { dist1 = cv; way1 = j1; }
                }
            }

            if (sc0) { float del = D - dist0; v0 -= del; u_sh[p_lo] += del; }
            if (sc1) { float del = D - dist1; v1 -= del; u_sh[p_hi] += del; }
            if (t == 0) u_sh[row] += D;

            int j0 = j1;
            while (true) {
                int lane0 = j0 >> 1;
                bool odd = (j0 & 1) != 0;
                int jp = rdlane_i(odd ? way1 : way0, lane0);
                int pv;
                if (jp == 128) pv = row;
                else           pv = rdlane_i((jp & 1) ? p_hi : p_lo, jp >> 1);
                if (!odd && lane0 == t) p_lo = pv;
                if ( odd && lane0 == t) p_hi = pv;
                if (jp == 128) break;
                j0 = jp;
            }
            wave_fence();
        }

        // --- total optimal cost for this batch ---
        float tsum = A[p_lo * K_PTS + c0] + A[p_hi * K_PTS + c1];
#pragma unroll
        for (int m = 1; m <= 32; m <<= 1)
            tsum += __shfl_xor(tsum, m, 64);
        if (t == 0) atomicAdd(out, tsum * inv_total);
    }
}

extern "C" void kernel_launch(void* const* d_in, const int* in_sizes, int n_in,
                              void* d_out, int out_size, void* d_ws, size_t ws_size,
                              hipStream_t stream) {
    const float* X = (const float*)d_in[0];
    const float* Y = (const float*)d_in[1];
    float* out = (float*)d_out;

    const int total = in_sizes[0];              // B*K*D
    const int B = total / (K_PTS * DIM);
    const float inv_total = 1.0f / (float)total;

    hipMemsetAsync(out, 0, out_size * sizeof(float), stream);
    hungarian_mse_kernel<<<dim3(B), dim3(256), 0, stream>>>(X, Y, out, inv_total);
}